// Round 9
// baseline (97.103 us; speedup 1.0000x reference)
//
#include <hip/hip_runtime.h>
#include <math.h>

// StructLoss: sqrt(mean(|grads4(outputs - labels)|) + 1e-16)
// grads4 linear -> compute on d = outputs - labels.
// [B=16, C=6, H=512, W=512] fp32; mean over B*4C*H*W.
//
// Flat rolling window (R2 skeleton) with 2-row bodies: each body issues 8
// independent dwordx4 (rows r+2, r+3 of both arrays) back-to-back, then
// stencils row r (no dependence), converts r+2 (vmcnt(4)), stencils r+1,
// converts r+3 (vmcnt(0), covered by two stencils). All raw loads are
// consumed in the SAME body -> compiler cannot sink them across
// iterations (the R3/R6/R7 failure). Clamped addresses + 0/1 mask for
// image edges; lane shuffles for column edges. Fused last-block
// deterministic mean+sqrt tail. XCD-chunked block swizzle for halo L2
// locality.

#define NTHREADS 256
#define STRIP 8
#define WV 512
#define HT 512
#define PLANES 96
#define STRIPS_PER_PLANE (HT / STRIP)                    // 64
#define TOTAL_WAVES (PLANES * STRIPS_PER_PLANE)          // 6144
#define NBLOCKS (TOTAL_WAVES / (NTHREADS / 64))          // 1536
#define NXCD 8

struct Raw { float4 o0, o1, l0, l1; };
struct Row { float d[8]; float eL, eR; };

__device__ __forceinline__ Raw load_row(const float* __restrict__ ob,
                                        const float* __restrict__ lb, int r) {
    const int gr = min(max(r, 0), HT - 1);       // clamp: address always valid
    const size_t off = (size_t)gr * WV;
    Raw w;
    w.o0 = *reinterpret_cast<const float4*>(ob + off);
    w.o1 = *reinterpret_cast<const float4*>(ob + off + 4);
    w.l0 = *reinterpret_cast<const float4*>(lb + off);
    w.l1 = *reinterpret_cast<const float4*>(lb + off + 4);
    return w;
}

__device__ __forceinline__ Row convert(const Raw& w, int lane, float m) {
    Row row;
    row.d[0] = m * (w.o0.x - w.l0.x); row.d[1] = m * (w.o0.y - w.l0.y);
    row.d[2] = m * (w.o0.z - w.l0.z); row.d[3] = m * (w.o0.w - w.l0.w);
    row.d[4] = m * (w.o1.x - w.l1.x); row.d[5] = m * (w.o1.y - w.l1.y);
    row.d[6] = m * (w.o1.z - w.l1.z); row.d[7] = m * (w.o1.w - w.l1.w);
    const float up = __shfl_up(row.d[7], 1, 64);
    const float dn = __shfl_down(row.d[0], 1, 64);
    row.eL = (lane == 0)  ? 0.f : up;    // col 8l-1 (image zero-pad)
    row.eR = (lane == 63) ? 0.f : dn;    // col 8l+8 (image zero-pad)
    return row;
}

__device__ __forceinline__ float stencil(const Row& rp, const Row& rc,
                                         const Row& rn) {
    float a = 0.f;
    #pragma unroll
    for (int k = 0; k < 8; ++k) {
        const float cL = (k > 0) ? rc.d[k - 1] : rc.eL;
        const float cR = (k < 7) ? rc.d[k + 1] : rc.eR;
        const float pL = (k > 0) ? rp.d[k - 1] : rp.eL;
        const float pR = (k < 7) ? rp.d[k + 1] : rp.eR;
        const float nL = (k > 0) ? rn.d[k - 1] : rn.eL;
        const float nR = (k < 7) ? rn.d[k + 1] : rn.eR;

        const float gy = rp.d[k] - rn.d[k];   // x[i-1,j]   - x[i+1,j]
        const float gx = cL - cR;             // x[i,j-1]   - x[i,j+1]
        const float gD = pL - nR;             // x[i-1,j-1] - x[i+1,j+1]
        const float gd = pR - nL;             // x[i-1,j+1] - x[i+1,j-1]
        a += fabsf(gy) + fabsf(gx) + fabsf(gD) + fabsf(gd);
    }
    return a;
}

__global__ __launch_bounds__(NTHREADS) void struct_loss(
        const float* __restrict__ out_p, const float* __restrict__ lab_p,
        float* __restrict__ partials, unsigned* __restrict__ counter,
        float* __restrict__ out, double inv_count) {
    const int tid  = threadIdx.x;
    const int lane = tid & 63;
    const int wid  = tid >> 6;

    // XCD-chunked swizzle (1536 % 8 == 0 -> bijective): each XCD gets a
    // contiguous run of 192 work-blocks so adjacent strips (shared halo
    // rows) hit the same per-XCD L2.
    const int wb   = (blockIdx.x & (NXCD - 1)) * (NBLOCKS / NXCD)
                   + (blockIdx.x >> 3);
    const int gw   = wb * (NTHREADS / 64) + wid;           // 0..6143
    const int plane = gw >> 6;                             // / STRIPS_PER_PLANE
    const int r0    = (gw & (STRIPS_PER_PLANE - 1)) * STRIP;

    const size_t base = (size_t)plane * (HT * WV) + lane * 8;
    const float* ob = out_p + base;
    const float* lb = lab_p + base;

    float acc = 0.f;

    // Prologue: window rows r0-1, r0, r0+1.
    Raw A = load_row(ob, lb, r0 - 1);
    Raw B = load_row(ob, lb, r0);
    Raw C = load_row(ob, lb, r0 + 1);
    Row rp = convert(A, lane, (r0 > 0) ? 1.f : 0.f);
    Row rc = convert(B, lane, 1.f);
    Row rn = convert(C, lane, 1.f);

    #pragma unroll
    for (int b = 0; b < STRIP / 2; ++b) {       // body = rows r, r+1
        const int r = r0 + 2 * b;

        // Issue both rows' loads back-to-back (8 dwordx4 in flight).
        Raw D = load_row(ob, lb, r + 2);
        Raw E;
        if (b < STRIP / 2 - 1) E = load_row(ob, lb, r + 3);

        acc += stencil(rp, rc, rn);             // row r: no dep on D/E

        const float mD = (r + 2 < HT) ? 1.f : 0.f;
        Row rn2 = convert(D, lane, mD);         // waits first 4 loads only

        acc += stencil(rc, rn, rn2);            // row r+1

        if (b < STRIP / 2 - 1) {
            const float mE = (r + 3 < HT) ? 1.f : 0.f;
            Row rn3 = convert(E, lane, mE);     // covered by 2 stencils
            rp = rn; rc = rn2; rn = rn3;
        }
    }

    // ---- wave + block reduction ----
    #pragma unroll
    for (int off = 32; off > 0; off >>= 1)
        acc += __shfl_down(acc, off, 64);

    __shared__ float smem[NTHREADS / 64];
    if (lane == 0) smem[wid] = acc;
    __syncthreads();

    __shared__ bool amLast;
    if (tid == 0) {
        float s = 0.f;
        #pragma unroll
        for (int w = 0; w < NTHREADS / 64; ++w) s += smem[w];
        partials[blockIdx.x] = s;
        __threadfence();                          // publish partial
        const unsigned old = atomicAdd(counter, 1u);
        amLast = (old == (unsigned)(NBLOCKS - 1));
    }
    __syncthreads();

    if (amLast) {
        __threadfence();                          // see all partials
        double s = 0.0;
        for (int i = tid; i < NBLOCKS; i += NTHREADS)  // fixed order: determ.
            s += (double)partials[i];
        #pragma unroll
        for (int off = 32; off > 0; off >>= 1)
            s += __shfl_down(s, off, 64);
        __shared__ double dsm[NTHREADS / 64];
        if (lane == 0) dsm[wid] = s;
        __syncthreads();
        if (tid == 0) {
            double t = 0.0;
            #pragma unroll
            for (int w = 0; w < NTHREADS / 64; ++w) t += dsm[w];
            out[0] = (float)sqrt(t * inv_count + 1e-16);
        }
    }
}

extern "C" void kernel_launch(void* const* d_in, const int* in_sizes, int n_in,
                              void* d_out, int out_size, void* d_ws, size_t ws_size,
                              hipStream_t stream) {
    const float* outputs = (const float*)d_in[0];
    const float* labels  = (const float*)d_in[1];
    float* out = (float*)d_out;

    unsigned* counter = (unsigned*)d_ws;            // u32 at offset 0
    float* partials   = (float*)d_ws + 16;          // 1536 floats at 64 B off

    const double inv_count = 1.0 / (16.0 * 24.0 * 512.0 * 512.0);

    hipMemsetAsync(counter, 0, sizeof(unsigned), stream);
    struct_loss<<<NBLOCKS, NTHREADS, 0, stream>>>(outputs, labels, partials,
                                                  counter, out, inv_count);
}